// Round 9
// baseline (609.644 us; speedup 1.0000x reference)
//
#include <hip/hip_runtime.h>
#include <hip/hip_bf16.h>
#include <math.h>

#define NN 100000
#define EE 1600000
#define IN_F 128
#define HH 4
#define DD 32
#define LL 3
#define NB_ 391          // node buckets of 256: ceil(N/256)
#define EPB 4096         // edges per block in bucket hist/partition

typedef __bf16 bf16x8 __attribute__((ext_vector_type(8)));
typedef float f32x4 __attribute__((ext_vector_type(4)));
typedef unsigned int u32x4 __attribute__((ext_vector_type(4)));

static __device__ __forceinline__ unsigned short f2bf(float x) {
    __hip_bfloat16 b = __float2bfloat16(x);
    return *reinterpret_cast<unsigned short*>(&b);
}

// W [l][k][n] fp32 -> wt [l][n][k] bf16 (B-operand layout for MFMA)
__global__ void wt_kernel(const float* __restrict__ Ws,
                          unsigned short* __restrict__ wt) {
    const int i = blockIdx.x * blockDim.x + threadIdx.x;   // L*128*128
    if (i >= LL * IN_F * IN_F) return;
    const int l = i >> 14, r = i & 16383;
    const int n = r >> 7, k = r & 127;
    wt[i] = f2bf(Ws[(l << 14) + k * IN_F + n]);
}

// ---------------------------------------------------------------------------
// MFMA GEMM: ft = x @ W (bf16 in, fp32 acc), fused el/er dots from fp32 acc.
// F32A=true: A operand is fp32 (layer 0 reads h directly, converts in-reg).
// ft store goes through an LDS transpose (row stride 136 ushort = 272 B,
// padded vs 256 to spread banks) so global stores are coalesced dwordx4
// instead of 32 scalar ushort stores.  er is written into the packed
// erden[N][8] (er at +h, den at +4+h) so attn_out touches one line per dst.
// ---------------------------------------------------------------------------
template <bool F32A>
__global__ __launch_bounds__(256) void gemm_mfma_kernel(
    const void* __restrict__ a_src,
    const unsigned short* __restrict__ wt,    // [128 n][128 k] bf16
    const float* __restrict__ al,
    const float* __restrict__ ar,
    unsigned short* __restrict__ ft_bf,
    float* __restrict__ el,          // [N][4]
    float* __restrict__ erden) {     // [N][8]: er at +h
    __shared__ unsigned short lds_t[4 * 16 * 136];   // 17408 B
    const int wave = (blockIdx.x * blockDim.x + threadIdx.x) >> 6;
    const int w = (threadIdx.x >> 6) & 3;
    const int lane = threadIdx.x & 63;
    const int base = wave * 16;
    const bool active = base < NN;
    const int c = lane & 15;
    const int quad = lane >> 4;

    f32x4 acc[8];
    if (active) {
        const int arow = min(base + c, NN - 1);
        bf16x8 a[4];
        if (F32A) {
            const float4* xp = (const float4*)((const float*)a_src + (size_t)arow * IN_F);
#pragma unroll
            for (int kc = 0; kc < 4; ++kc) {
                const float4 lo = xp[(kc * 4 + quad) * 2];
                const float4 hi = xp[(kc * 4 + quad) * 2 + 1];
                union { unsigned short us[8]; bf16x8 v; } u;
                u.us[0] = f2bf(lo.x); u.us[1] = f2bf(lo.y);
                u.us[2] = f2bf(lo.z); u.us[3] = f2bf(lo.w);
                u.us[4] = f2bf(hi.x); u.us[5] = f2bf(hi.y);
                u.us[6] = f2bf(hi.z); u.us[7] = f2bf(hi.w);
                a[kc] = u.v;
            }
        } else {
            const bf16x8* ap = (const bf16x8*)((const unsigned short*)a_src + (size_t)arow * IN_F);
#pragma unroll
            for (int kc = 0; kc < 4; ++kc) a[kc] = ap[kc * 4 + quad];
        }

#pragma unroll
        for (int nt = 0; nt < 8; ++nt) {
            const bf16x8* bp = (const bf16x8*)(wt + (size_t)(nt * 16 + c) * IN_F);
            f32x4 d = {0.f, 0.f, 0.f, 0.f};
#pragma unroll
            for (int kc = 0; kc < 4; ++kc)
                d = __builtin_amdgcn_mfma_f32_16x16x32_bf16(a[kc], bp[kc * 4 + quad], d, 0, 0, 0);
            acc[nt] = d;
        }

        // transpose into LDS: row = quad*4+r (16 rows), col = nt*16+c
#pragma unroll
        for (int nt = 0; nt < 8; ++nt)
#pragma unroll
            for (int r = 0; r < 4; ++r)
                lds_t[w * 2176 + (quad * 4 + r) * 136 + nt * 16 + c] = f2bf(acc[nt][r]);
    }
    __syncthreads();
    if (active) {
        // coalesced ft store: 4 x dwordx4 per lane
        const int row = lane >> 2;
        const int seg = lane & 3;
        const int n_row = base + row;
        if (n_row < NN) {
            const unsigned short* lp = &lds_t[w * 2176 + row * 136 + seg * 8];
            uint4* gp = (uint4*)(ft_bf + (size_t)n_row * IN_F) + seg;
#pragma unroll
            for (int it = 0; it < 4; ++it)
                gp[it * 4] = *(const uint4*)(lp + it * 32);
        }

        // attention dots from fp32 acc: head h covers tiles 2h, 2h+1
#pragma unroll
        for (int h = 0; h < 4; ++h) {
            float pl[4], pr[4];
#pragma unroll
            for (int r = 0; r < 4; ++r) {
                const float a0 = acc[2 * h][r], a1 = acc[2 * h + 1][r];
                pl[r] = a0 * al[h * 32 + c] + a1 * al[h * 32 + 16 + c];
                pr[r] = a0 * ar[h * 32 + c] + a1 * ar[h * 32 + 16 + c];
            }
#pragma unroll
            for (int off = 8; off >= 1; off >>= 1) {
#pragma unroll
                for (int r = 0; r < 4; ++r) {
                    pl[r] += __shfl_xor(pl[r], off);
                    pr[r] += __shfl_xor(pr[r], off);
                }
            }
            if (c == 0) {
#pragma unroll
                for (int r = 0; r < 4; ++r) {
                    const int n = base + quad * 4 + r;
                    if (n < NN) {
                        el[n * HH + h] = pl[r];
                        erden[(size_t)n * 8 + h] = pr[r];
                    }
                }
            }
        }
    }
}

// ---------------------------------------------------------------------------
// CSR build, two-pass bucket radix by dst>>8 (391 buckets of 256 nodes).
// ---------------------------------------------------------------------------

__global__ void bucket_hist_kernel(const int* __restrict__ dst,
                                   int* __restrict__ tot) {
    __shared__ int l[NB_];
    for (int b = threadIdx.x; b < NB_; b += 256) l[b] = 0;
    __syncthreads();
    const int e0 = blockIdx.x * EPB;
    const int e1 = min(e0 + EPB, EE);
    for (int e = e0 + threadIdx.x; e < e1; e += 256)
        atomicAdd(&l[dst[e] >> 8], 1);
    __syncthreads();
    for (int b = threadIdx.x; b < NB_; b += 256)
        if (l[b]) atomicAdd(&tot[b], l[b]);
}

__global__ void bucket_scan_kernel(const int* __restrict__ tot,
                                   int* __restrict__ base,
                                   int* __restrict__ cur) {
    __shared__ int tmp[512];
    const int tid = threadIdx.x;
    int v = (tid < NB_) ? tot[tid] : 0;
    tmp[tid] = v;
    __syncthreads();
    for (int off = 1; off < 512; off <<= 1) {
        int t = (tid >= off) ? tmp[tid - off] : 0;
        __syncthreads();
        if (tid >= off) tmp[tid] += t;
        __syncthreads();
    }
    if (tid < NB_) {
        const int excl = tmp[tid] - v;
        base[tid] = excl;
        cur[tid] = excl;
    }
    if (tid == 0) base[NB_] = EE;
}

__global__ void partition_kernel(const int* __restrict__ src,
                                 const int* __restrict__ dst,
                                 int* __restrict__ cur,
                                 int* __restrict__ bkt) {
    __shared__ int lcnt[NB_];
    __shared__ int lbase[NB_];
    const int tid = threadIdx.x;
    const int e0 = blockIdx.x * EPB;
    const int e1 = min(e0 + EPB, EE);
    for (int b = tid; b < NB_; b += 256) lcnt[b] = 0;
    __syncthreads();
    for (int e = e0 + tid; e < e1; e += 256)
        atomicAdd(&lcnt[dst[e] >> 8], 1);
    __syncthreads();
    for (int b = tid; b < NB_; b += 256) {
        const int c = lcnt[b];
        lbase[b] = c ? atomicAdd(&cur[b], c) : 0;
        lcnt[b] = 0;
    }
    __syncthreads();
    for (int e = e0 + tid; e < e1; e += 256) {
        const int d = dst[e];
        const int b = d >> 8;
        const int idx = atomicAdd(&lcnt[b], 1);
        bkt[lbase[b] + idx] = ((d & 255) << 17) | src[e];
    }
}

__global__ void bucket_sort_kernel(const int* __restrict__ bkt,
                                   const int* __restrict__ base,
                                   int* __restrict__ cnt,
                                   int* __restrict__ row_start,
                                   int* __restrict__ ssrc) {
    __shared__ int lcnt[256];
    __shared__ int loff[256];
    const int tid = threadIdx.x;
    const int b = blockIdx.x;
    const int s0 = base[b], s1 = base[b + 1];
    lcnt[tid] = 0;
    __syncthreads();
    for (int p = s0 + tid; p < s1; p += 256)
        atomicAdd(&lcnt[bkt[p] >> 17], 1);
    __syncthreads();
    const int v = lcnt[tid];
    loff[tid] = v;
    __syncthreads();
    for (int off = 1; off < 256; off <<= 1) {
        int t = (tid >= off) ? loff[tid - off] : 0;
        __syncthreads();
        if (tid >= off) loff[tid] += t;
        __syncthreads();
    }
    const int excl = loff[tid] - v;          // exclusive local offset
    const int n = b * 256 + tid;
    if (n < NN) {
        cnt[n] = v;
        row_start[n] = s0 + excl;
    }
    __syncthreads();
    loff[tid] = excl;
    lcnt[tid] = 0;
    __syncthreads();
    for (int p = s0 + tid; p < s1; p += 256) {
        const int w = bkt[p];
        const int dl = w >> 17;
        const int idx = atomicAdd(&lcnt[dl], 1);
        ssrc[s0 + loff[dl] + idx] = w & 0x1FFFF;
    }
}

// ---------------------------------------------------------------------------
// Fused aggregation: one wave per dst node.  Lane decomposition:
//   e4 = lane>>4  (edge slot 0..3), fq = lane&15 (16 B = 8 features).
// Row gathers are uint4 (full rows; round-7 showed sub-row slicing is a
// 2.5x over-fetch).  Streaming traffic (ssrc, xin, outputs) is nontemporal
// so it doesn't consume L2 ways needed by the ft/el gather working set.
// ---------------------------------------------------------------------------
__global__ void aggregate_kernel(const uint4* __restrict__ ft4,  // [N][16]
                                 const float* __restrict__ el,   // [N][4]
                                 float* __restrict__ erden,      // [N][8]
                                 const float* __restrict__ xin,  // [N][128]
                                 const float* __restrict__ bias, // [128]
                                 const int* __restrict__ row_start,
                                 const int* __restrict__ cnt,
                                 const int* __restrict__ ssrc,
                                 float* __restrict__ out,
                                 unsigned short* __restrict__ out_bf) {
    const int n = (blockIdx.x * blockDim.x + threadIdx.x) >> 6;
    const int lane = threadIdx.x & 63;
    if (n >= NN) return;
    const int e4 = lane >> 4;            // edge slot
    const int fq = lane & 15;            // feature quad (features fq*8..fq*8+7)
    const int h = fq >> 2;               // head owning these features

    const float ern = erden[(size_t)n * 8 + h];
    const int beg = row_start[n];
    const int end = beg + cnt[n];

    float acc[8] = {0.f, 0.f, 0.f, 0.f, 0.f, 0.f, 0.f, 0.f};
    float den = 0.f;

#define ACC8(E, W)                                                        \
    acc[0] = fmaf(E, __uint_as_float((W).x << 16), acc[0]);               \
    acc[1] = fmaf(E, __uint_as_float((W).x & 0xffff0000u), acc[1]);       \
    acc[2] = fmaf(E, __uint_as_float((W).y << 16), acc[2]);               \
    acc[3] = fmaf(E, __uint_as_float((W).y & 0xffff0000u), acc[3]);       \
    acc[4] = fmaf(E, __uint_as_float((W).z << 16), acc[4]);               \
    acc[5] = fmaf(E, __uint_as_float((W).z & 0xffff0000u), acc[5]);       \
    acc[6] = fmaf(E, __uint_as_float((W).w << 16), acc[6]);               \
    acc[7] = fmaf(E, __uint_as_float((W).w & 0xffff0000u), acc[7]);

    int p = beg;
    for (; p + 16 <= end; p += 16) {
        const int s0 = __builtin_nontemporal_load(&ssrc[p + e4]);
        const int s1 = __builtin_nontemporal_load(&ssrc[p + 4 + e4]);
        const int s2 = __builtin_nontemporal_load(&ssrc[p + 8 + e4]);
        const int s3 = __builtin_nontemporal_load(&ssrc[p + 12 + e4]);
        float ev0 = el[s0 * HH + h] + ern;
        float ev1 = el[s1 * HH + h] + ern;
        float ev2 = el[s2 * HH + h] + ern;
        float ev3 = el[s3 * HH + h] + ern;
        const uint4 w0 = ft4[(size_t)s0 * 16 + fq];
        const uint4 w1 = ft4[(size_t)s1 * 16 + fq];
        const uint4 w2 = ft4[(size_t)s2 * 16 + fq];
        const uint4 w3 = ft4[(size_t)s3 * 16 + fq];
        ev0 = ev0 > 0.f ? ev0 : 0.2f * ev0;
        ev1 = ev1 > 0.f ? ev1 : 0.2f * ev1;
        ev2 = ev2 > 0.f ? ev2 : 0.2f * ev2;
        ev3 = ev3 > 0.f ? ev3 : 0.2f * ev3;
        const float e0 = __expf(ev0);
        const float e1 = __expf(ev1);
        const float e2 = __expf(ev2);
        const float e3 = __expf(ev3);
        den += (e0 + e1) + (e2 + e3);
        ACC8(e0, w0)
        ACC8(e1, w1)
        ACC8(e2, w2)
        ACC8(e3, w3)
    }
    for (; p < end; p += 4) {
        const int pe = p + e4;
        const bool valid = pe < end;
        // invalid slots replay a valid row (beg < end here) with e=0 so no
        // garbage bf16 bits enter an fma.
        const int s = __builtin_nontemporal_load(&ssrc[valid ? pe : beg]);
        float ev = el[s * HH + h] + ern;
        const uint4 w = ft4[(size_t)s * 16 + fq];
        ev = ev > 0.f ? ev : 0.2f * ev;
        const float e1 = valid ? __expf(ev) : 0.f;
        den += e1;
        ACC8(e1, w)
    }
#undef ACC8

    // reduce across the 4 edge slots (lanes differing in bits 4..5)
#pragma unroll
    for (int off = 16; off < 64; off <<= 1) {
        den += __shfl_xor(den, off);
#pragma unroll
        for (int k = 0; k < 8; ++k) acc[k] += __shfl_xor(acc[k], off);
    }

    if (lane < 16) {
        if ((fq & 3) == 0) erden[(size_t)n * 8 + 4 + h] = den;
        const float inv = 1.f / fmaxf(den, 1e-9f);
        const f32x4 xi0 = __builtin_nontemporal_load((const f32x4*)xin + (size_t)n * 32 + fq * 2);
        const f32x4 xi1 = __builtin_nontemporal_load((const f32x4*)xin + (size_t)n * 32 + fq * 2 + 1);
        const float4 bb0 = ((const float4*)bias)[fq * 2];
        const float4 bb1 = ((const float4*)bias)[fq * 2 + 1];
        float v[8];
        v[0] = acc[0] * inv + xi0.x + bb0.x;
        v[1] = acc[1] * inv + xi0.y + bb0.y;
        v[2] = acc[2] * inv + xi0.z + bb0.z;
        v[3] = acc[3] * inv + xi0.w + bb0.w;
        v[4] = acc[4] * inv + xi1.x + bb1.x;
        v[5] = acc[5] * inv + xi1.y + bb1.y;
        v[6] = acc[6] * inv + xi1.z + bb1.z;
        v[7] = acc[7] * inv + xi1.w + bb1.w;
#pragma unroll
        for (int k = 0; k < 8; ++k)
            v[k] = v[k] > 0.f ? v[k] : __expf(v[k]) - 1.f;
        f32x4 o0 = {v[0], v[1], v[2], v[3]};
        f32x4 o1 = {v[4], v[5], v[6], v[7]};
        __builtin_nontemporal_store(o0, (f32x4*)out + (size_t)n * 32 + fq * 2);
        __builtin_nontemporal_store(o1, (f32x4*)out + (size_t)n * 32 + fq * 2 + 1);
        u32x4 ob;
        ob.x = (unsigned int)f2bf(v[0]) | ((unsigned int)f2bf(v[1]) << 16);
        ob.y = (unsigned int)f2bf(v[2]) | ((unsigned int)f2bf(v[3]) << 16);
        ob.z = (unsigned int)f2bf(v[4]) | ((unsigned int)f2bf(v[5]) << 16);
        ob.w = (unsigned int)f2bf(v[6]) | ((unsigned int)f2bf(v[7]) << 16);
        __builtin_nontemporal_store(ob, (u32x4*)out_bf + (size_t)n * 16 + fq);
    }
}

// ---------------------------------------------------------------------------
// a[e,h] = exp(leaky(el[src]+er[dst])) / den[dst]  (bit-identical __expf)
// er/den packed in erden[N][8]: one line-touch per dst instead of two.
// ---------------------------------------------------------------------------
__global__ void attn_out_kernel(const int* __restrict__ src,
                                const int* __restrict__ dst,
                                const float* __restrict__ el,
                                const float* __restrict__ erden,
                                float* __restrict__ a_out) {
    const int e = blockIdx.x * blockDim.x + threadIdx.x;
    if (e >= EE) return;
    const int s = __builtin_nontemporal_load(&src[e]);
    const int d = __builtin_nontemporal_load(&dst[e]);
    const float4 l4 = ((const float4*)el)[s];
    const float4 r4 = *(const float4*)(erden + (size_t)d * 8);
    const float4 dn = *(const float4*)(erden + (size_t)d * 8 + 4);
    float v[4] = {l4.x + r4.x, l4.y + r4.y, l4.z + r4.z, l4.w + r4.w};
    float dv[4] = {dn.x, dn.y, dn.z, dn.w};
    f32x4 o;
#pragma unroll
    for (int hh = 0; hh < 4; ++hh) {
        float t = v[hh] > 0.f ? v[hh] : 0.2f * v[hh];
        o[hh] = __expf(t) / fmaxf(dv[hh], 1e-9f);
    }
    __builtin_nontemporal_store(o, (f32x4*)a_out + e);
}

extern "C" void kernel_launch(void* const* d_in, const int* in_sizes, int n_in,
                              void* d_out, int out_size, void* d_ws, size_t ws_size,
                              hipStream_t stream) {
    const float* h    = (const float*)d_in[0];
    const int*   src  = (const int*)  d_in[1];
    const int*   dst  = (const int*)  d_in[2];
    const float* Ws   = (const float*)d_in[3];
    const float* al   = (const float*)d_in[4];
    const float* ar   = (const float*)d_in[5];
    const float* bias = (const float*)d_in[6];

    float* out_x = (float*)d_out;                         // [N,128] fp32
    float* out_a = out_x + (size_t)NN * IN_F;             // [E,4] fp32
    // x_bf (N*128 bf16 = 25.6 MB) aliases the out_a region (E*4 f32 = 25.6 MB):
    // it holds aggregate's bf16 outputs (layer 1/2 GEMM inputs) during the
    // layer loop; attn_out overwrites it at the end.
    unsigned short* x_bf = (unsigned short*)out_a;

    // workspace layout: same total bytes as round 5 (el+er+den 12N floats ==
    // el 4N + erden 8N).
    char* ws = (char*)d_ws;
    unsigned short* ft_bf = (unsigned short*)ws;              // N*128 bf16
    float* bufA = (float*)(ft_bf + (size_t)NN * IN_F);        // N*128 f32
    float* el   = bufA + (size_t)NN * IN_F;                   // N*4
    float* erden= el + (size_t)NN * HH;                       // N*8 packed er|den
    int*   cnt        = (int*)(erden + (size_t)NN * 8);       // N
    int*   row_start  = cnt + NN;                             // N
    int*   bucket_tot = row_start + NN;                       // 512 (NB_ used)
    int*   bucket_base= bucket_tot + 512;                     // 512 (NB_+1 used)
    int*   bucket_cur = bucket_base + 512;                    // 512 (NB_ used)
    int*   ssrc       = bucket_cur + 512;                     // E
    unsigned short* wt = (unsigned short*)(ssrc + EE);        // 3*128*128 bf16
    // bkt (E ints, CSR-build scratch only) aliases bufA: bufA is first
    // written by layer-0 aggregate, strictly after bucket_sort has consumed bkt.
    int* bkt = (int*)bufA;

    // ---- one-time conversions + CSR build (identical every call) ----
    wt_kernel<<<(LL * IN_F * IN_F + 255) / 256, 256, 0, stream>>>(Ws, wt);

    hipMemsetAsync(bucket_tot, 0, 512 * sizeof(int), stream);
    const int ebks = (EE + EPB - 1) / EPB;   // 391
    bucket_hist_kernel<<<ebks, 256, 0, stream>>>(dst, bucket_tot);
    bucket_scan_kernel<<<1, 512, 0, stream>>>(bucket_tot, bucket_base, bucket_cur);
    partition_kernel<<<ebks, 256, 0, stream>>>(src, dst, bucket_cur, bkt);
    bucket_sort_kernel<<<NB_, 256, 0, stream>>>(bkt, bucket_base, cnt, row_start, ssrc);

    // layer schedule: L0: h->bufA, L1: bufA->out_x, L2: out_x->out_x
    const float* xin[LL]  = {h, bufA, out_x};
    float*       xout[LL] = {bufA, out_x, out_x};
    const int gemm_blocks = ((NN + 15) / 16 + 3) / 4;   // waves of 16 nodes, 4/block

    for (int i = 0; i < LL; ++i) {
        const float* all_ = al + (size_t)i * HH * DD;
        const float* arl = ar + (size_t)i * HH * DD;
        const float* bl  = bias + (size_t)i * HH * DD;

        if (i == 0) {
            gemm_mfma_kernel<true><<<gemm_blocks, 256, 0, stream>>>(
                (const void*)h, wt + (size_t)i * IN_F * IN_F, all_, arl, ft_bf, el, erden);
        } else {
            gemm_mfma_kernel<false><<<gemm_blocks, 256, 0, stream>>>(
                (const void*)x_bf, wt + (size_t)i * IN_F * IN_F, all_, arl, ft_bf, el, erden);
        }
        aggregate_kernel<<<(NN + 3) / 4, 256, 0, stream>>>(
            (const uint4*)ft_bf, el, erden, xin[i], bl, row_start, cnt, ssrc,
            xout[i], x_bf);
    }
    attn_out_kernel<<<(EE + 255) / 256, 256, 0, stream>>>(src, dst, el, erden, out_a);
}

// Round 10
// 577.003 us; speedup vs baseline: 1.0566x; 1.0566x over previous
//
#include <hip/hip_runtime.h>
#include <hip/hip_bf16.h>
#include <math.h>

#define NN 100000
#define EE 1600000
#define IN_F 128
#define HH 4
#define DD 32
#define LL 3
#define NB_ 391          // node buckets of 256: ceil(N/256)
#define EPB 4096         // edges per block in bucket hist/partition

typedef __bf16 bf16x8 __attribute__((ext_vector_type(8)));
typedef float f32x4 __attribute__((ext_vector_type(4)));

static __device__ __forceinline__ unsigned short f2bf(float x) {
    __hip_bfloat16 b = __float2bfloat16(x);
    return *reinterpret_cast<unsigned short*>(&b);
}

// W [l][k][n] fp32 -> wt [l][n][k] bf16 (B-operand layout for MFMA)
__global__ void wt_kernel(const float* __restrict__ Ws,
                          unsigned short* __restrict__ wt) {
    const int i = blockIdx.x * blockDim.x + threadIdx.x;   // L*128*128
    if (i >= LL * IN_F * IN_F) return;
    const int l = i >> 14, r = i & 16383;
    const int n = r >> 7, k = r & 127;
    wt[i] = f2bf(Ws[(l << 14) + k * IN_F + n]);
}

// ---------------------------------------------------------------------------
// MFMA GEMM: ft = x @ W (bf16 in, fp32 acc), fused el/er dots from fp32 acc.
// F32A=true: A operand is fp32 (layer 0 reads h directly, converts in-reg).
// ft store goes through an LDS transpose (row stride 136 ushort = 272 B)
// so global stores are coalesced dwordx4 (round-9 measured this a win).
// er goes into packed erden[N][8] (er at +h, den at +4+h).
// ---------------------------------------------------------------------------
template <bool F32A>
__global__ __launch_bounds__(256) void gemm_mfma_kernel(
    const void* __restrict__ a_src,
    const unsigned short* __restrict__ wt,    // [128 n][128 k] bf16
    const float* __restrict__ al,
    const float* __restrict__ ar,
    unsigned short* __restrict__ ft_bf,
    float* __restrict__ el,          // [N][4]
    float* __restrict__ erden) {     // [N][8]: er at +h
    __shared__ unsigned short lds_t[4 * 16 * 136];   // 17408 B
    const int wave = (blockIdx.x * blockDim.x + threadIdx.x) >> 6;
    const int w = (threadIdx.x >> 6) & 3;
    const int lane = threadIdx.x & 63;
    const int base = wave * 16;
    const bool active = base < NN;
    const int c = lane & 15;
    const int quad = lane >> 4;

    f32x4 acc[8];
    if (active) {
        const int arow = min(base + c, NN - 1);
        bf16x8 a[4];
        if (F32A) {
            const float4* xp = (const float4*)((const float*)a_src + (size_t)arow * IN_F);
#pragma unroll
            for (int kc = 0; kc < 4; ++kc) {
                const float4 lo = xp[(kc * 4 + quad) * 2];
                const float4 hi = xp[(kc * 4 + quad) * 2 + 1];
                union { unsigned short us[8]; bf16x8 v; } u;
                u.us[0] = f2bf(lo.x); u.us[1] = f2bf(lo.y);
                u.us[2] = f2bf(lo.z); u.us[3] = f2bf(lo.w);
                u.us[4] = f2bf(hi.x); u.us[5] = f2bf(hi.y);
                u.us[6] = f2bf(hi.z); u.us[7] = f2bf(hi.w);
                a[kc] = u.v;
            }
        } else {
            const bf16x8* ap = (const bf16x8*)((const unsigned short*)a_src + (size_t)arow * IN_F);
#pragma unroll
            for (int kc = 0; kc < 4; ++kc) a[kc] = ap[kc * 4 + quad];
        }

#pragma unroll
        for (int nt = 0; nt < 8; ++nt) {
            const bf16x8* bp = (const bf16x8*)(wt + (size_t)(nt * 16 + c) * IN_F);
            f32x4 d = {0.f, 0.f, 0.f, 0.f};
#pragma unroll
            for (int kc = 0; kc < 4; ++kc)
                d = __builtin_amdgcn_mfma_f32_16x16x32_bf16(a[kc], bp[kc * 4 + quad], d, 0, 0, 0);
            acc[nt] = d;
        }

        // transpose into LDS: row = quad*4+r (16 rows), col = nt*16+c
#pragma unroll
        for (int nt = 0; nt < 8; ++nt)
#pragma unroll
            for (int r = 0; r < 4; ++r)
                lds_t[w * 2176 + (quad * 4 + r) * 136 + nt * 16 + c] = f2bf(acc[nt][r]);
    }
    __syncthreads();
    if (active) {
        // coalesced ft store: 4 x dwordx4 per lane
        const int row = lane >> 2;
        const int seg = lane & 3;
        const int n_row = base + row;
        if (n_row < NN) {
            const unsigned short* lp = &lds_t[w * 2176 + row * 136 + seg * 8];
            uint4* gp = (uint4*)(ft_bf + (size_t)n_row * IN_F) + seg;
#pragma unroll
            for (int it = 0; it < 4; ++it)
                gp[it * 4] = *(const uint4*)(lp + it * 32);
        }

        // attention dots from fp32 acc: head h covers tiles 2h, 2h+1
#pragma unroll
        for (int h = 0; h < 4; ++h) {
            float pl[4], pr[4];
#pragma unroll
            for (int r = 0; r < 4; ++r) {
                const float a0 = acc[2 * h][r], a1 = acc[2 * h + 1][r];
                pl[r] = a0 * al[h * 32 + c] + a1 * al[h * 32 + 16 + c];
                pr[r] = a0 * ar[h * 32 + c] + a1 * ar[h * 32 + 16 + c];
            }
#pragma unroll
            for (int off = 8; off >= 1; off >>= 1) {
#pragma unroll
                for (int r = 0; r < 4; ++r) {
                    pl[r] += __shfl_xor(pl[r], off);
                    pr[r] += __shfl_xor(pr[r], off);
                }
            }
            if (c == 0) {
#pragma unroll
                for (int r = 0; r < 4; ++r) {
                    const int n = base + quad * 4 + r;
                    if (n < NN) {
                        el[n * HH + h] = pl[r];
                        erden[(size_t)n * 8 + h] = pr[r];
                    }
                }
            }
        }
    }
}

// ---------------------------------------------------------------------------
// CSR build, two-pass bucket radix by dst>>8 (391 buckets of 256 nodes).
// ---------------------------------------------------------------------------

__global__ void bucket_hist_kernel(const int* __restrict__ dst,
                                   int* __restrict__ tot) {
    __shared__ int l[NB_];
    for (int b = threadIdx.x; b < NB_; b += 256) l[b] = 0;
    __syncthreads();
    const int e0 = blockIdx.x * EPB;
    const int e1 = min(e0 + EPB, EE);
    for (int e = e0 + threadIdx.x; e < e1; e += 256)
        atomicAdd(&l[dst[e] >> 8], 1);
    __syncthreads();
    for (int b = threadIdx.x; b < NB_; b += 256)
        if (l[b]) atomicAdd(&tot[b], l[b]);
}

__global__ void bucket_scan_kernel(const int* __restrict__ tot,
                                   int* __restrict__ base,
                                   int* __restrict__ cur) {
    __shared__ int tmp[512];
    const int tid = threadIdx.x;
    int v = (tid < NB_) ? tot[tid] : 0;
    tmp[tid] = v;
    __syncthreads();
    for (int off = 1; off < 512; off <<= 1) {
        int t = (tid >= off) ? tmp[tid - off] : 0;
        __syncthreads();
        if (tid >= off) tmp[tid] += t;
        __syncthreads();
    }
    if (tid < NB_) {
        const int excl = tmp[tid] - v;
        base[tid] = excl;
        cur[tid] = excl;
    }
    if (tid == 0) base[NB_] = EE;
}

__global__ void partition_kernel(const int* __restrict__ src,
                                 const int* __restrict__ dst,
                                 int* __restrict__ cur,
                                 int* __restrict__ bkt) {
    __shared__ int lcnt[NB_];
    __shared__ int lbase[NB_];
    const int tid = threadIdx.x;
    const int e0 = blockIdx.x * EPB;
    const int e1 = min(e0 + EPB, EE);
    for (int b = tid; b < NB_; b += 256) lcnt[b] = 0;
    __syncthreads();
    for (int e = e0 + tid; e < e1; e += 256)
        atomicAdd(&lcnt[dst[e] >> 8], 1);
    __syncthreads();
    for (int b = tid; b < NB_; b += 256) {
        const int c = lcnt[b];
        lbase[b] = c ? atomicAdd(&cur[b], c) : 0;
        lcnt[b] = 0;
    }
    __syncthreads();
    for (int e = e0 + tid; e < e1; e += 256) {
        const int d = dst[e];
        const int b = d >> 8;
        const int idx = atomicAdd(&lcnt[b], 1);
        bkt[lbase[b] + idx] = ((d & 255) << 17) | src[e];
    }
}

__global__ void bucket_sort_kernel(const int* __restrict__ bkt,
                                   const int* __restrict__ base,
                                   int* __restrict__ cnt,
                                   int* __restrict__ row_start,
                                   int* __restrict__ ssrc) {
    __shared__ int lcnt[256];
    __shared__ int loff[256];
    const int tid = threadIdx.x;
    const int b = blockIdx.x;
    const int s0 = base[b], s1 = base[b + 1];
    lcnt[tid] = 0;
    __syncthreads();
    for (int p = s0 + tid; p < s1; p += 256)
        atomicAdd(&lcnt[bkt[p] >> 17], 1);
    __syncthreads();
    const int v = lcnt[tid];
    loff[tid] = v;
    __syncthreads();
    for (int off = 1; off < 256; off <<= 1) {
        int t = (tid >= off) ? loff[tid - off] : 0;
        __syncthreads();
        if (tid >= off) loff[tid] += t;
        __syncthreads();
    }
    const int excl = loff[tid] - v;          // exclusive local offset
    const int n = b * 256 + tid;
    if (n < NN) {
        cnt[n] = v;
        row_start[n] = s0 + excl;
    }
    __syncthreads();
    loff[tid] = excl;
    lcnt[tid] = 0;
    __syncthreads();
    for (int p = s0 + tid; p < s1; p += 256) {
        const int w = bkt[p];
        const int dl = w >> 17;
        const int idx = atomicAdd(&lcnt[dl], 1);
        ssrc[s0 + loff[dl] + idx] = w & 0x1FFFF;
    }
}

// ---------------------------------------------------------------------------
// Fused aggregation: one wave per dst node.  Lane decomposition:
//   e4 = lane>>4  (edge slot 0..3), fq = lane&15 (16 B = 8 features).
// Row gathers are uint4 (full rows; round-7 showed sub-row slicing is a
// 2.5x over-fetch).  Plain loads/stores only — round-9 measured nontemporal
// hints cost +11 us/layer (ssrc loads on the critical path lost L2).
// ---------------------------------------------------------------------------
__global__ void aggregate_kernel(const uint4* __restrict__ ft4,  // [N][16]
                                 const float* __restrict__ el,   // [N][4]
                                 float* __restrict__ erden,      // [N][8]
                                 const float* __restrict__ xin,  // [N][128]
                                 const float* __restrict__ bias, // [128]
                                 const int* __restrict__ row_start,
                                 const int* __restrict__ cnt,
                                 const int* __restrict__ ssrc,
                                 float* __restrict__ out,
                                 unsigned short* __restrict__ out_bf) {
    const int n = (blockIdx.x * blockDim.x + threadIdx.x) >> 6;
    const int lane = threadIdx.x & 63;
    if (n >= NN) return;
    const int e4 = lane >> 4;            // edge slot
    const int fq = lane & 15;            // feature quad (features fq*8..fq*8+7)
    const int h = fq >> 2;               // head owning these features

    const float ern = erden[(size_t)n * 8 + h];
    const int beg = row_start[n];
    const int end = beg + cnt[n];

    float acc[8] = {0.f, 0.f, 0.f, 0.f, 0.f, 0.f, 0.f, 0.f};
    float den = 0.f;

#define ACC8(E, W)                                                        \
    acc[0] = fmaf(E, __uint_as_float((W).x << 16), acc[0]);               \
    acc[1] = fmaf(E, __uint_as_float((W).x & 0xffff0000u), acc[1]);       \
    acc[2] = fmaf(E, __uint_as_float((W).y << 16), acc[2]);               \
    acc[3] = fmaf(E, __uint_as_float((W).y & 0xffff0000u), acc[3]);       \
    acc[4] = fmaf(E, __uint_as_float((W).z << 16), acc[4]);               \
    acc[5] = fmaf(E, __uint_as_float((W).z & 0xffff0000u), acc[5]);       \
    acc[6] = fmaf(E, __uint_as_float((W).w << 16), acc[6]);               \
    acc[7] = fmaf(E, __uint_as_float((W).w & 0xffff0000u), acc[7]);

    int p = beg;
    for (; p + 16 <= end; p += 16) {
        const int s0 = ssrc[p + e4];
        const int s1 = ssrc[p + 4 + e4];
        const int s2 = ssrc[p + 8 + e4];
        const int s3 = ssrc[p + 12 + e4];
        float ev0 = el[s0 * HH + h] + ern;
        float ev1 = el[s1 * HH + h] + ern;
        float ev2 = el[s2 * HH + h] + ern;
        float ev3 = el[s3 * HH + h] + ern;
        const uint4 w0 = ft4[(size_t)s0 * 16 + fq];
        const uint4 w1 = ft4[(size_t)s1 * 16 + fq];
        const uint4 w2 = ft4[(size_t)s2 * 16 + fq];
        const uint4 w3 = ft4[(size_t)s3 * 16 + fq];
        ev0 = ev0 > 0.f ? ev0 : 0.2f * ev0;
        ev1 = ev1 > 0.f ? ev1 : 0.2f * ev1;
        ev2 = ev2 > 0.f ? ev2 : 0.2f * ev2;
        ev3 = ev3 > 0.f ? ev3 : 0.2f * ev3;
        const float e0 = __expf(ev0);
        const float e1 = __expf(ev1);
        const float e2 = __expf(ev2);
        const float e3 = __expf(ev3);
        den += (e0 + e1) + (e2 + e3);
        ACC8(e0, w0)
        ACC8(e1, w1)
        ACC8(e2, w2)
        ACC8(e3, w3)
    }
    for (; p < end; p += 4) {
        const int pe = p + e4;
        const bool valid = pe < end;
        // invalid slots replay a valid row (beg < end here) with e=0 so no
        // garbage bf16 bits enter an fma.
        const int s = ssrc[valid ? pe : beg];
        float ev = el[s * HH + h] + ern;
        const uint4 w = ft4[(size_t)s * 16 + fq];
        ev = ev > 0.f ? ev : 0.2f * ev;
        const float e1 = valid ? __expf(ev) : 0.f;
        den += e1;
        ACC8(e1, w)
    }
#undef ACC8

    // reduce across the 4 edge slots (lanes differing in bits 4..5)
#pragma unroll
    for (int off = 16; off < 64; off <<= 1) {
        den += __shfl_xor(den, off);
#pragma unroll
        for (int k = 0; k < 8; ++k) acc[k] += __shfl_xor(acc[k], off);
    }

    if (lane < 16) {
        if ((fq & 3) == 0) erden[(size_t)n * 8 + 4 + h] = den;
        const float inv = 1.f / fmaxf(den, 1e-9f);
        const float4 xi0 = ((const float4*)xin)[(size_t)n * 32 + fq * 2];
        const float4 xi1 = ((const float4*)xin)[(size_t)n * 32 + fq * 2 + 1];
        const float4 bb0 = ((const float4*)bias)[fq * 2];
        const float4 bb1 = ((const float4*)bias)[fq * 2 + 1];
        float v[8];
        v[0] = acc[0] * inv + xi0.x + bb0.x;
        v[1] = acc[1] * inv + xi0.y + bb0.y;
        v[2] = acc[2] * inv + xi0.z + bb0.z;
        v[3] = acc[3] * inv + xi0.w + bb0.w;
        v[4] = acc[4] * inv + xi1.x + bb1.x;
        v[5] = acc[5] * inv + xi1.y + bb1.y;
        v[6] = acc[6] * inv + xi1.z + bb1.z;
        v[7] = acc[7] * inv + xi1.w + bb1.w;
#pragma unroll
        for (int k = 0; k < 8; ++k)
            v[k] = v[k] > 0.f ? v[k] : __expf(v[k]) - 1.f;
        ((float4*)out)[(size_t)n * 32 + fq * 2] = make_float4(v[0], v[1], v[2], v[3]);
        ((float4*)out)[(size_t)n * 32 + fq * 2 + 1] = make_float4(v[4], v[5], v[6], v[7]);
        uint4 ob;
        ob.x = (unsigned int)f2bf(v[0]) | ((unsigned int)f2bf(v[1]) << 16);
        ob.y = (unsigned int)f2bf(v[2]) | ((unsigned int)f2bf(v[3]) << 16);
        ob.z = (unsigned int)f2bf(v[4]) | ((unsigned int)f2bf(v[5]) << 16);
        ob.w = (unsigned int)f2bf(v[6]) | ((unsigned int)f2bf(v[7]) << 16);
        ((uint4*)out_bf)[(size_t)n * 16 + fq] = ob;
    }
}

// ---------------------------------------------------------------------------
// a[e,h] = exp(leaky(el[src]+er[dst])) / den[dst]  (bit-identical __expf)
// er/den packed in erden[N][8]: one line-touch per dst instead of two.
// ---------------------------------------------------------------------------
__global__ void attn_out_kernel(const int* __restrict__ src,
                                const int* __restrict__ dst,
                                const float* __restrict__ el,
                                const float* __restrict__ erden,
                                float* __restrict__ a_out) {
    const int e = blockIdx.x * blockDim.x + threadIdx.x;
    if (e >= EE) return;
    const int s = src[e], d = dst[e];
    const float4 l4 = ((const float4*)el)[s];
    const float4 r4 = *(const float4*)(erden + (size_t)d * 8);
    const float4 dn = *(const float4*)(erden + (size_t)d * 8 + 4);
    float v[4] = {l4.x + r4.x, l4.y + r4.y, l4.z + r4.z, l4.w + r4.w};
    float dv[4] = {dn.x, dn.y, dn.z, dn.w};
    float4 o;
    float* op = &o.x;
#pragma unroll
    for (int hh = 0; hh < 4; ++hh) {
        float t = v[hh] > 0.f ? v[hh] : 0.2f * v[hh];
        op[hh] = __expf(t) / fmaxf(dv[hh], 1e-9f);
    }
    ((float4*)a_out)[e] = o;
}

extern "C" void kernel_launch(void* const* d_in, const int* in_sizes, int n_in,
                              void* d_out, int out_size, void* d_ws, size_t ws_size,
                              hipStream_t stream) {
    const float* h    = (const float*)d_in[0];
    const int*   src  = (const int*)  d_in[1];
    const int*   dst  = (const int*)  d_in[2];
    const float* Ws   = (const float*)d_in[3];
    const float* al   = (const float*)d_in[4];
    const float* ar   = (const float*)d_in[5];
    const float* bias = (const float*)d_in[6];

    float* out_x = (float*)d_out;                         // [N,128] fp32
    float* out_a = out_x + (size_t)NN * IN_F;             // [E,4] fp32
    // x_bf (N*128 bf16 = 25.6 MB) aliases the out_a region (E*4 f32 = 25.6 MB):
    // it holds aggregate's bf16 outputs (layer 1/2 GEMM inputs) during the
    // layer loop; attn_out overwrites it at the end.
    unsigned short* x_bf = (unsigned short*)out_a;

    // workspace layout: same total bytes as round 5 (el+er+den 12N floats ==
    // el 4N + erden 8N).
    char* ws = (char*)d_ws;
    unsigned short* ft_bf = (unsigned short*)ws;              // N*128 bf16
    float* bufA = (float*)(ft_bf + (size_t)NN * IN_F);        // N*128 f32
    float* el   = bufA + (size_t)NN * IN_F;                   // N*4
    float* erden= el + (size_t)NN * HH;                       // N*8 packed er|den
    int*   cnt        = (int*)(erden + (size_t)NN * 8);       // N
    int*   row_start  = cnt + NN;                             // N
    int*   bucket_tot = row_start + NN;                       // 512 (NB_ used)
    int*   bucket_base= bucket_tot + 512;                     // 512 (NB_+1 used)
    int*   bucket_cur = bucket_base + 512;                    // 512 (NB_ used)
    int*   ssrc       = bucket_cur + 512;                     // E
    unsigned short* wt = (unsigned short*)(ssrc + EE);        // 3*128*128 bf16
    // bkt (E ints, CSR-build scratch only) aliases bufA: bufA is first
    // written by layer-0 aggregate, strictly after bucket_sort has consumed bkt.
    int* bkt = (int*)bufA;

    // ---- one-time conversions + CSR build (identical every call) ----
    wt_kernel<<<(LL * IN_F * IN_F + 255) / 256, 256, 0, stream>>>(Ws, wt);

    hipMemsetAsync(bucket_tot, 0, 512 * sizeof(int), stream);
    const int ebks = (EE + EPB - 1) / EPB;   // 391
    bucket_hist_kernel<<<ebks, 256, 0, stream>>>(dst, bucket_tot);
    bucket_scan_kernel<<<1, 512, 0, stream>>>(bucket_tot, bucket_base, bucket_cur);
    partition_kernel<<<ebks, 256, 0, stream>>>(src, dst, bucket_cur, bkt);
    bucket_sort_kernel<<<NB_, 256, 0, stream>>>(bkt, bucket_base, cnt, row_start, ssrc);

    // layer schedule: L0: h->bufA, L1: bufA->out_x, L2: out_x->out_x
    const float* xin[LL]  = {h, bufA, out_x};
    float*       xout[LL] = {bufA, out_x, out_x};
    const int gemm_blocks = ((NN + 15) / 16 + 3) / 4;   // waves of 16 nodes, 4/block

    for (int i = 0; i < LL; ++i) {
        const float* all_ = al + (size_t)i * HH * DD;
        const float* arl = ar + (size_t)i * HH * DD;
        const float* bl  = bias + (size_t)i * HH * DD;

        if (i == 0) {
            gemm_mfma_kernel<true><<<gemm_blocks, 256, 0, stream>>>(
                (const void*)h, wt + (size_t)i * IN_F * IN_F, all_, arl, ft_bf, el, erden);
        } else {
            gemm_mfma_kernel<false><<<gemm_blocks, 256, 0, stream>>>(
                (const void*)x_bf, wt + (size_t)i * IN_F * IN_F, all_, arl, ft_bf, el, erden);
        }
        aggregate_kernel<<<(NN + 3) / 4, 256, 0, stream>>>(
            (const uint4*)ft_bf, el, erden, xin[i], bl, row_start, cnt, ssrc,
            xout[i], x_bf);
    }
    attn_out_kernel<<<(EE + 255) / 256, 256, 0, stream>>>(src, dst, el, erden, out_a);
}